// Round 1
// 892.678 us; speedup vs baseline: 1.4241x; 1.4241x over previous
//
#include <hip/hip_runtime.h>

// ---------------------------------------------------------------------------
// GCN 3-layer forward on MI355X — Round 5: fp16 MFMA GEMM.
// R4 counters: gemm_nt_kernel = 212us x2 + ~106us, MfmaUtil 0, VALUBusy 47%
// -> fp32 VALU GEMM at 62 TF while matrix cores (2.4 PF f16) idle.
// Change: all 2-byte storage bf16 -> fp16 (10-bit mantissa, 8x lower rounding,
// values O(1-30) << 65504 so range-safe); GEMM = mfma_f32_16x16x32_f16 with
// fp32 accumulation, 128x128 tile / BK=64 / 4 waves, XOR-swizzled LDS
// (kills the stride-128B 16-way ds_read_b128 bank conflict).
// Agg now writes fp16 A-planes (halves agg write + GEMM A read traffic).
// ---------------------------------------------------------------------------

constexpr int DIN = 128;
constexpr int DH  = 256;

typedef _Float16 f16x8 __attribute__((ext_vector_type(8)));
typedef float    f32x4 __attribute__((ext_vector_type(4)));

__device__ __forceinline__ float h2f(unsigned short u) {
    _Float16 h;
    __builtin_memcpy(&h, &u, 2);
    return (float)h;
}
__device__ __forceinline__ unsigned short f2h(float f) {
    _Float16 h = (_Float16)f;
    unsigned short u;
    __builtin_memcpy(&u, &h, 2);
    return u;
}

__global__ void zero_int_kernel(int* __restrict__ p, int n) {
    int i = blockIdx.x * blockDim.x + threadIdx.x;
    if (i < n) p[i] = 0;
}

__global__ void count_deg_kernel(const int* __restrict__ col, int E, int* __restrict__ deg) {
    int e = blockIdx.x * blockDim.x + threadIdx.x;
    if (e < E) atomicAdd(&deg[col[e]], 1);
}

// Single-block exclusive scan: deg[0..N) -> rowptr[0..N], rowptr[N] = E.
__global__ __launch_bounds__(1024) void scan_kernel(const int* __restrict__ deg,
                                                    int* __restrict__ rowptr, int N) {
    __shared__ int sums[1024];
    int t = threadIdx.x;
    int chunk = (N + 1023) / 1024;
    int s0 = t * chunk, s1 = min(N, s0 + chunk);
    int local = 0;
    for (int i = s0; i < s1; i++) local += deg[i];
    sums[t] = local;
    __syncthreads();
    for (int off = 1; off < 1024; off <<= 1) {
        int v = (t >= off) ? sums[t - off] : 0;
        __syncthreads();
        sums[t] += v;
        __syncthreads();
    }
    int prefix = (t == 0) ? 0 : sums[t - 1];
    for (int i = s0; i < s1; i++) { rowptr[i] = prefix; prefix += deg[i]; }
    if (t == 1023) rowptr[N] = sums[1023];
}

// dinv = 1/sqrt(deg+1); also zero deg for reuse as the CSR fill cursor.
__global__ void dinv_kernel(int* __restrict__ deg, float* __restrict__ dinv, int N) {
    int n = blockIdx.x * blockDim.x + threadIdx.x;
    if (n < N) {
        float d = (float)(deg[n] + 1);
        dinv[n] = 1.0f / sqrtf(d);
        deg[n] = 0;
    }
}

__global__ void fill_csr_kernel(const int* __restrict__ row, const int* __restrict__ col,
                                const int* __restrict__ rowptr, int* __restrict__ cnt,
                                const float* __restrict__ dinv,
                                int* __restrict__ csr_src, float* __restrict__ csr_w, int E) {
    int e = blockIdx.x * blockDim.x + threadIdx.x;
    if (e >= E) return;
    int r = row[e], c = col[e];
    int pos = rowptr[c] + atomicAdd(&cnt[c], 1);
    csr_src[pos] = r;
    csr_w[pos]   = dinv[r] * dinv[c];
}

// fp32 -> fp16 cast (RNE), 4 elems/thread.
__global__ void cast_f16_kernel(const float4* __restrict__ in, ushort4* __restrict__ out, int n4) {
    int i = blockIdx.x * blockDim.x + threadIdx.x;
    if (i >= n4) return;
    float4 v = in[i];
    ushort4 o;
    o.x = f2h(v.x); o.y = f2h(v.y); o.z = f2h(v.z); o.w = f2h(v.w);
    out[i] = o;
}

// One L-lane group per node; lane handles 4 fp16 elems (8B load). L = D/4.
// in: fp16 rows [N][D]; out: fp16 rows [N][D]. Self-loop fused into init.
template<int D>
__global__ __launch_bounds__(256) void agg_gather_f16_kernel(const int* __restrict__ rowptr,
                                                             const int* __restrict__ csr_src,
                                                             const float* __restrict__ csr_w,
                                                             const float* __restrict__ dinv,
                                                             const ushort4* __restrict__ in,
                                                             ushort4* __restrict__ out, int N) {
    constexpr int L = D / 4;                 // 64 (D=256) or 32 (D=128)
    constexpr int GPB = 256 / L;
    int n = blockIdx.x * GPB + threadIdx.x / L;
    if (n >= N) return;
    int lane = threadIdx.x % L;

    float di = dinv[n];
    float s = di * di;
    ushort4 sv = in[(size_t)n * L + lane];
    float4 acc = make_float4(h2f(sv.x) * s, h2f(sv.y) * s, h2f(sv.z) * s, h2f(sv.w) * s);

    int start = rowptr[n], end = rowptr[n + 1];
    for (int j0 = start; j0 < end; j0 += L) {
        int nb = end - j0; if (nb > L) nb = L;
        int   src = 0;
        float w   = 0.0f;
        if (lane < nb) { src = csr_src[j0 + lane]; w = csr_w[j0 + lane]; }
        if constexpr (L == 64) {
            // one node per wave: broadcast via v_readlane (uniform t, VALU-only)
            for (int t = 0; t < nb; ++t) {
                int   r  = __builtin_amdgcn_readlane(src, t);
                float ww = __int_as_float(__builtin_amdgcn_readlane(__float_as_int(w), t));
                ushort4 v = in[(size_t)r * L + lane];
                acc.x += ww * h2f(v.x); acc.y += ww * h2f(v.y);
                acc.z += ww * h2f(v.z); acc.w += ww * h2f(v.w);
            }
        } else {
            for (int t = 0; t < nb; ++t) {
                int   r  = __shfl(src, t, L);
                float ww = __shfl(w,   t, L);
                ushort4 v = in[(size_t)r * L + lane];
                acc.x += ww * h2f(v.x); acc.y += ww * h2f(v.y);
                acc.z += ww * h2f(v.z); acc.w += ww * h2f(v.w);
            }
        }
    }
    ushort4 o;
    o.x = f2h(acc.x); o.y = f2h(acc.y); o.z = f2h(acc.z); o.w = f2h(acc.w);
    out[(size_t)n * L + lane] = o;
}

// C[n][m] = sum_k A[n][k]*W[m][k]; A:[N,K] fp16, W:[256,K] fp16 (pre-cast).
// MFMA f16, fp32 accum. 128x128 tile, BK=64, 4 waves (2x2), 64x64 per wave.
// LDS: A-tile + W-tile, [128][64] fp16, XOR-swizzled 16B slots
// (slot ^= row&7) -> 2-way max bank aliasing on ds_read_b128 (free, m136).
template<int K, bool RELU, typename OT>
__global__ __launch_bounds__(256) void gemm_nt_mfma_kernel(const unsigned short* __restrict__ A,
                                                           const unsigned short* __restrict__ Wh,
                                                           OT* __restrict__ C, int N) {
    __shared__ __align__(16) unsigned short As[128 * 64];
    __shared__ __align__(16) unsigned short Ws[128 * 64];
    int tid  = threadIdx.x;
    int lane = tid & 63;
    int wave = tid >> 6;
    int wr = wave >> 1, wc = wave & 1;       // wave grid 2x2
    int m0 = blockIdx.x * 128;               // output rows (nodes)
    int c0 = blockIdx.y * 128;               // output cols (0 or 128)

    f32x4 acc[4][4];
    #pragma unroll
    for (int i = 0; i < 4; i++)
        #pragma unroll
        for (int j = 0; j < 4; j++)
            #pragma unroll
            for (int r = 0; r < 4; r++) acc[i][j][r] = 0.0f;

    int srow  = tid >> 3;                    // 0..31: staging row within pass
    int sslot = tid & 7;                     // 16B slot within row (8 slots = 64 fp16)

    for (int k0 = 0; k0 < K; k0 += 64) {
        // ---- stage A[m0..m0+127][k0..k0+63] and W[c0..c0+127][k0..k0+63]
        #pragma unroll
        for (int q = 0; q < 4; ++q) {
            int row = q * 32 + srow;
            int byteoff = row * 128 + ((sslot ^ (row & 7)) << 4);
            int gr = m0 + row;
            if (gr >= N) gr = N - 1;         // clamp: tail rows computed, never stored
            f16x8 va = *(const f16x8*)(A + (size_t)gr * K + k0 + sslot * 8);
            *(f16x8*)((char*)As + byteoff) = va;
            int gw = c0 + row;               // always < 256
            f16x8 vw = *(const f16x8*)(Wh + (size_t)gw * K + k0 + sslot * 8);
            *(f16x8*)((char*)Ws + byteoff) = vw;
        }
        __syncthreads();

        // ---- 2 x K=32 MFMA steps over this BK=64 tile
        #pragma unroll
        for (int kk = 0; kk < 2; ++kk) {
            int slot = kk * 4 + (lane >> 4);
            f16x8 a[4], b[4];
            #pragma unroll
            for (int i = 0; i < 4; i++) {
                int row = wr * 64 + i * 16 + (lane & 15);
                a[i] = *(const f16x8*)((const char*)As + row * 128 + ((slot ^ (row & 7)) << 4));
            }
            #pragma unroll
            for (int j = 0; j < 4; j++) {
                int row = wc * 64 + j * 16 + (lane & 15);
                b[j] = *(const f16x8*)((const char*)Ws + row * 128 + ((slot ^ (row & 7)) << 4));
            }
            #pragma unroll
            for (int i = 0; i < 4; i++)
                #pragma unroll
                for (int j = 0; j < 4; j++)
                    acc[i][j] = __builtin_amdgcn_mfma_f32_16x16x32_f16(a[i], b[j], acc[i][j], 0, 0, 0);
        }
        __syncthreads();
    }

    // ---- epilogue: D lane map (verified m89): col = lane&15, row = (lane>>4)*4 + r
    int r4 = (lane >> 4) * 4;
    int cn = lane & 15;
    #pragma unroll
    for (int i = 0; i < 4; i++) {
        #pragma unroll
        for (int r = 0; r < 4; r++) {
            int g_r = m0 + wr * 64 + i * 16 + r4 + r;
            if (g_r >= N) continue;
            #pragma unroll
            for (int j = 0; j < 4; j++) {
                float v = acc[i][j][r];
                if (RELU) v = fmaxf(v, 0.f);
                int col = c0 + wc * 64 + j * 16 + cn;
                if constexpr (sizeof(OT) == 4) {
                    ((float*)C)[(size_t)g_r * DH + col] = v;
                } else {
                    ((unsigned short*)C)[(size_t)g_r * DH + col] = f2h(v);
                }
            }
        }
    }
}

extern "C" void kernel_launch(void* const* d_in, const int* in_sizes, int n_in,
                              void* d_out, int out_size, void* d_ws, size_t ws_size,
                              hipStream_t stream) {
    const float* x  = (const float*)d_in[0];
    const int*   ei = (const int*)d_in[1];
    const float* W1 = (const float*)d_in[2];
    const float* W2 = (const float*)d_in[3];
    const float* W3 = (const float*)d_in[4];
    float* out = (float*)d_out;

    int N = in_sizes[0] / DIN;
    int E = in_sizes[1] / 2;
    const int* row = ei;         // sources
    const int* col = ei + E;     // targets (aggregation)

    char* ws = (char*)d_ws;
    int*   deg     = (int*)ws;                      // N ints (later: fill cursor)
    float* dinv    = (float*)(ws + 400000);         // N floats
    int*   rowptr  = (int*)(ws + 800000);           // N+1 ints
    int*   csr_src = (int*)(ws + 1200016);          // E ints
    float* csr_w   = (float*)(ws + 7600016);        // E floats
    unsigned short* bufA = (unsigned short*)(ws + 14000128);  // N*256 fp16 agg out (A operand)
    unsigned short* w1h  = (unsigned short*)(ws + 65200128);  // 256*128 fp16
    unsigned short* w2h  = (unsigned short*)(ws + 65265664);  // 256*256 fp16
    unsigned short* w3h  = (unsigned short*)(ws + 65396736);  // 256*256 fp16

    // fp16 staging for gather inputs lives inside d_out (dead/overwritten):
    // x_f16 (N*128, 25.6MB) is dead before GEMM1 writes h (N*256 fp16, 51.2MB)
    // over it; GEMM3 fully overwrites d_out with the fp32 result.
    unsigned short* hb = (unsigned short*)d_out;

    dim3 b256(256);

    // CSR build: deg -> rowptr -> dinv (+cursor reset) -> fill
    zero_int_kernel<<<dim3((N + 255) / 256), b256, 0, stream>>>(deg, N);
    count_deg_kernel<<<dim3((E + 255) / 256), b256, 0, stream>>>(col, E, deg);
    scan_kernel<<<dim3(1), dim3(1024), 0, stream>>>(deg, rowptr, N);
    dinv_kernel<<<dim3((N + 255) / 256), b256, 0, stream>>>(deg, dinv, N);
    fill_csr_kernel<<<dim3((E + 255) / 256), b256, 0, stream>>>(
        row, col, rowptr, deg, dinv, csr_src, csr_w, E);

    // Pre-cast weights + x to fp16
    cast_f16_kernel<<<dim3((N * (DIN / 4) + 255) / 256), b256, 0, stream>>>(
        (const float4*)x, (ushort4*)hb, N * (DIN / 4));
    cast_f16_kernel<<<dim3((DH * DIN / 4 + 255) / 256), b256, 0, stream>>>(
        (const float4*)W1, (ushort4*)w1h, DH * DIN / 4);
    cast_f16_kernel<<<dim3((DH * DH / 4 + 255) / 256), b256, 0, stream>>>(
        (const float4*)W2, (ushort4*)w2h, DH * DH / 4);
    cast_f16_kernel<<<dim3((DH * DH / 4 + 255) / 256), b256, 0, stream>>>(
        (const float4*)W3, (ushort4*)w3h, DH * DH / 4);

    dim3 ggrid((N + 127) / 128, 2);

    // ---- Layer 1: s = A_n x16; h1 = f16(relu(s @ W1^T))
    agg_gather_f16_kernel<DIN><<<dim3((N + 7) / 8), b256, 0, stream>>>(
        rowptr, csr_src, csr_w, dinv, (const ushort4*)hb, (ushort4*)bufA, N);
    gemm_nt_mfma_kernel<DIN, true, unsigned short><<<ggrid, b256, 0, stream>>>(
        bufA, w1h, hb, N);

    // ---- Layer 2: s = A_n h1; h2 = f16(relu(s @ W2^T))
    agg_gather_f16_kernel<DH><<<dim3((N + 3) / 4), b256, 0, stream>>>(
        rowptr, csr_src, csr_w, dinv, (const ushort4*)hb, (ushort4*)bufA, N);
    gemm_nt_mfma_kernel<DH, true, unsigned short><<<ggrid, b256, 0, stream>>>(
        bufA, w2h, hb, N);

    // ---- Layer 3: s = A_n h2; out = s @ W3^T (fp32, full overwrite of d_out)
    agg_gather_f16_kernel<DH><<<dim3((N + 3) / 4), b256, 0, stream>>>(
        rowptr, csr_src, csr_w, dinv, (const ushort4*)hb, (ushort4*)bufA, N);
    gemm_nt_mfma_kernel<DH, false, float><<<ggrid, b256, 0, stream>>>(
        bufA, w3h, out, N);
}

// Round 2
// 743.907 us; speedup vs baseline: 1.7089x; 1.2000x over previous
//
#include <hip/hip_runtime.h>

// ---------------------------------------------------------------------------
// GCN 3-layer forward on MI355X — Round 6: parallel CSR scan.
// R5 counters: scan_kernel (single-block 1024t exclusive scan of deg[100K])
// = 163us/iter at 0.156% occupancy -- pure serialization on the critical
// path. Replace with 3-phase multi-block scan (98 blk chunk-sums -> 1-blk
// scan of block sums -> 98 blk local scan + add prefix). dinv + deg-reset
// fused into phase 3 (deletes dinv_kernel dispatch).
// GEMM (fp16 MFMA, R5) and gathers unchanged.
// ---------------------------------------------------------------------------

constexpr int DIN = 128;
constexpr int DH  = 256;

typedef _Float16 f16x8 __attribute__((ext_vector_type(8)));
typedef float    f32x4 __attribute__((ext_vector_type(4)));

__device__ __forceinline__ float h2f(unsigned short u) {
    _Float16 h;
    __builtin_memcpy(&h, &u, 2);
    return (float)h;
}
__device__ __forceinline__ unsigned short f2h(float f) {
    _Float16 h = (_Float16)f;
    unsigned short u;
    __builtin_memcpy(&u, &h, 2);
    return u;
}

__global__ void zero_int_kernel(int* __restrict__ p, int n) {
    int i = blockIdx.x * blockDim.x + threadIdx.x;
    if (i < n) p[i] = 0;
}

__global__ void count_deg_kernel(const int* __restrict__ col, int E, int* __restrict__ deg) {
    int e = blockIdx.x * blockDim.x + threadIdx.x;
    if (e < E) atomicAdd(&deg[col[e]], 1);
}

// ---- 3-phase multi-block exclusive scan over deg[0..N) -> rowptr[0..N] ----
// Phase 1: block b sums deg[b*1024 .. b*1024+1024) -> bsum[b].
__global__ __launch_bounds__(256) void scan_p1_kernel(const int* __restrict__ deg,
                                                      int* __restrict__ bsum, int N) {
    int t = threadIdx.x;
    int base = blockIdx.x * 1024 + t * 4;
    int s = 0;
    #pragma unroll
    for (int k = 0; k < 4; k++) { int i = base + k; if (i < N) s += deg[i]; }
    __shared__ int red[256];
    red[t] = s;
    __syncthreads();
    for (int off = 128; off > 0; off >>= 1) {
        if (t < off) red[t] += red[t + off];
        __syncthreads();
    }
    if (t == 0) bsum[blockIdx.x] = red[0];
}

// Phase 2: single block, in-place exclusive scan of bsum[0..nb) (nb ~ 98).
__global__ __launch_bounds__(1024) void scan_p2_kernel(int* __restrict__ bsum, int nb) {
    __shared__ int sums[1024];
    int t = threadIdx.x;
    int chunk = (nb + 1023) / 1024;
    int s0 = t * chunk, s1 = min(nb, s0 + chunk);
    int local = 0;
    for (int i = s0; i < s1; i++) local += bsum[i];
    sums[t] = local;
    __syncthreads();
    for (int off = 1; off < 1024; off <<= 1) {
        int v = (t >= off) ? sums[t - off] : 0;
        __syncthreads();
        sums[t] += v;
        __syncthreads();
    }
    int prefix = (t == 0) ? 0 : sums[t - 1];
    for (int i = s0; i < s1; i++) { int v = bsum[i]; bsum[i] = prefix; prefix += v; }
}

// Phase 3: block-local exclusive scan + bsum[b] offset -> rowptr.
// Fused: dinv[i] = 1/sqrt(deg[i]+1), deg[i] = 0 (CSR fill cursor reset).
__global__ __launch_bounds__(256) void scan_p3_kernel(int* __restrict__ deg,
                                                      const int* __restrict__ bsum,
                                                      int* __restrict__ rowptr,
                                                      float* __restrict__ dinv,
                                                      int N, int E) {
    int t = threadIdx.x;
    int base = blockIdx.x * 1024 + t * 4;
    int v[4];
    int s = 0;
    #pragma unroll
    for (int k = 0; k < 4; k++) {
        int i = base + k;
        v[k] = (i < N) ? deg[i] : 0;
        s += v[k];
    }
    __shared__ int sums[256];
    sums[t] = s;
    __syncthreads();
    for (int off = 1; off < 256; off <<= 1) {
        int u = (t >= off) ? sums[t - off] : 0;
        __syncthreads();
        sums[t] += u;
        __syncthreads();
    }
    int prefix = bsum[blockIdx.x] + ((t == 0) ? 0 : sums[t - 1]);
    #pragma unroll
    for (int k = 0; k < 4; k++) {
        int i = base + k;
        if (i < N) {
            rowptr[i] = prefix;
            dinv[i] = 1.0f / sqrtf((float)(v[k] + 1));
            deg[i] = 0;
        }
        prefix += v[k];
    }
    if (blockIdx.x == 0 && t == 0) rowptr[N] = E;
}

__global__ void fill_csr_kernel(const int* __restrict__ row, const int* __restrict__ col,
                                const int* __restrict__ rowptr, int* __restrict__ cnt,
                                const float* __restrict__ dinv,
                                int* __restrict__ csr_src, float* __restrict__ csr_w, int E) {
    int e = blockIdx.x * blockDim.x + threadIdx.x;
    if (e >= E) return;
    int r = row[e], c = col[e];
    int pos = rowptr[c] + atomicAdd(&cnt[c], 1);
    csr_src[pos] = r;
    csr_w[pos]   = dinv[r] * dinv[c];
}

// fp32 -> fp16 cast (RNE), 4 elems/thread.
__global__ void cast_f16_kernel(const float4* __restrict__ in, ushort4* __restrict__ out, int n4) {
    int i = blockIdx.x * blockDim.x + threadIdx.x;
    if (i >= n4) return;
    float4 v = in[i];
    ushort4 o;
    o.x = f2h(v.x); o.y = f2h(v.y); o.z = f2h(v.z); o.w = f2h(v.w);
    out[i] = o;
}

// One L-lane group per node; lane handles 4 fp16 elems (8B load). L = D/4.
// in: fp16 rows [N][D]; out: fp16 rows [N][D]. Self-loop fused into init.
template<int D>
__global__ __launch_bounds__(256) void agg_gather_f16_kernel(const int* __restrict__ rowptr,
                                                             const int* __restrict__ csr_src,
                                                             const float* __restrict__ csr_w,
                                                             const float* __restrict__ dinv,
                                                             const ushort4* __restrict__ in,
                                                             ushort4* __restrict__ out, int N) {
    constexpr int L = D / 4;                 // 64 (D=256) or 32 (D=128)
    constexpr int GPB = 256 / L;
    int n = blockIdx.x * GPB + threadIdx.x / L;
    if (n >= N) return;
    int lane = threadIdx.x % L;

    float di = dinv[n];
    float s = di * di;
    ushort4 sv = in[(size_t)n * L + lane];
    float4 acc = make_float4(h2f(sv.x) * s, h2f(sv.y) * s, h2f(sv.z) * s, h2f(sv.w) * s);

    int start = rowptr[n], end = rowptr[n + 1];
    for (int j0 = start; j0 < end; j0 += L) {
        int nb = end - j0; if (nb > L) nb = L;
        int   src = 0;
        float w   = 0.0f;
        if (lane < nb) { src = csr_src[j0 + lane]; w = csr_w[j0 + lane]; }
        if constexpr (L == 64) {
            // one node per wave: broadcast via v_readlane (uniform t, VALU-only)
            for (int t = 0; t < nb; ++t) {
                int   r  = __builtin_amdgcn_readlane(src, t);
                float ww = __int_as_float(__builtin_amdgcn_readlane(__float_as_int(w), t));
                ushort4 v = in[(size_t)r * L + lane];
                acc.x += ww * h2f(v.x); acc.y += ww * h2f(v.y);
                acc.z += ww * h2f(v.z); acc.w += ww * h2f(v.w);
            }
        } else {
            for (int t = 0; t < nb; ++t) {
                int   r  = __shfl(src, t, L);
                float ww = __shfl(w,   t, L);
                ushort4 v = in[(size_t)r * L + lane];
                acc.x += ww * h2f(v.x); acc.y += ww * h2f(v.y);
                acc.z += ww * h2f(v.z); acc.w += ww * h2f(v.w);
            }
        }
    }
    ushort4 o;
    o.x = f2h(acc.x); o.y = f2h(acc.y); o.z = f2h(acc.z); o.w = f2h(acc.w);
    out[(size_t)n * L + lane] = o;
}

// C[n][m] = sum_k A[n][k]*W[m][k]; A:[N,K] fp16, W:[256,K] fp16 (pre-cast).
// MFMA f16, fp32 accum. 128x128 tile, BK=64, 4 waves (2x2), 64x64 per wave.
// LDS: A-tile + W-tile, [128][64] fp16, XOR-swizzled 16B slots
// (slot ^= row&7) -> 2-way max bank aliasing on ds_read_b128 (free, m136).
template<int K, bool RELU, typename OT>
__global__ __launch_bounds__(256) void gemm_nt_mfma_kernel(const unsigned short* __restrict__ A,
                                                           const unsigned short* __restrict__ Wh,
                                                           OT* __restrict__ C, int N) {
    __shared__ __align__(16) unsigned short As[128 * 64];
    __shared__ __align__(16) unsigned short Ws[128 * 64];
    int tid  = threadIdx.x;
    int lane = tid & 63;
    int wave = tid >> 6;
    int wr = wave >> 1, wc = wave & 1;       // wave grid 2x2
    int m0 = blockIdx.x * 128;               // output rows (nodes)
    int c0 = blockIdx.y * 128;               // output cols (0 or 128)

    f32x4 acc[4][4];
    #pragma unroll
    for (int i = 0; i < 4; i++)
        #pragma unroll
        for (int j = 0; j < 4; j++)
            #pragma unroll
            for (int r = 0; r < 4; r++) acc[i][j][r] = 0.0f;

    int srow  = tid >> 3;                    // 0..31: staging row within pass
    int sslot = tid & 7;                     // 16B slot within row (8 slots = 64 fp16)

    for (int k0 = 0; k0 < K; k0 += 64) {
        // ---- stage A[m0..m0+127][k0..k0+63] and W[c0..c0+127][k0..k0+63]
        #pragma unroll
        for (int q = 0; q < 4; ++q) {
            int row = q * 32 + srow;
            int byteoff = row * 128 + ((sslot ^ (row & 7)) << 4);
            int gr = m0 + row;
            if (gr >= N) gr = N - 1;         // clamp: tail rows computed, never stored
            f16x8 va = *(const f16x8*)(A + (size_t)gr * K + k0 + sslot * 8);
            *(f16x8*)((char*)As + byteoff) = va;
            int gw = c0 + row;               // always < 256
            f16x8 vw = *(const f16x8*)(Wh + (size_t)gw * K + k0 + sslot * 8);
            *(f16x8*)((char*)Ws + byteoff) = vw;
        }
        __syncthreads();

        // ---- 2 x K=32 MFMA steps over this BK=64 tile
        #pragma unroll
        for (int kk = 0; kk < 2; ++kk) {
            int slot = kk * 4 + (lane >> 4);
            f16x8 a[4], b[4];
            #pragma unroll
            for (int i = 0; i < 4; i++) {
                int row = wr * 64 + i * 16 + (lane & 15);
                a[i] = *(const f16x8*)((const char*)As + row * 128 + ((slot ^ (row & 7)) << 4));
            }
            #pragma unroll
            for (int j = 0; j < 4; j++) {
                int row = wc * 64 + j * 16 + (lane & 15);
                b[j] = *(const f16x8*)((const char*)Ws + row * 128 + ((slot ^ (row & 7)) << 4));
            }
            #pragma unroll
            for (int i = 0; i < 4; i++)
                #pragma unroll
                for (int j = 0; j < 4; j++)
                    acc[i][j] = __builtin_amdgcn_mfma_f32_16x16x32_f16(a[i], b[j], acc[i][j], 0, 0, 0);
        }
        __syncthreads();
    }

    // ---- epilogue: D lane map (verified m89): col = lane&15, row = (lane>>4)*4 + r
    int r4 = (lane >> 4) * 4;
    int cn = lane & 15;
    #pragma unroll
    for (int i = 0; i < 4; i++) {
        #pragma unroll
        for (int r = 0; r < 4; r++) {
            int g_r = m0 + wr * 64 + i * 16 + r4 + r;
            if (g_r >= N) continue;
            #pragma unroll
            for (int j = 0; j < 4; j++) {
                float v = acc[i][j][r];
                if (RELU) v = fmaxf(v, 0.f);
                int col = c0 + wc * 64 + j * 16 + cn;
                if constexpr (sizeof(OT) == 4) {
                    ((float*)C)[(size_t)g_r * DH + col] = v;
                } else {
                    ((unsigned short*)C)[(size_t)g_r * DH + col] = f2h(v);
                }
            }
        }
    }
}

extern "C" void kernel_launch(void* const* d_in, const int* in_sizes, int n_in,
                              void* d_out, int out_size, void* d_ws, size_t ws_size,
                              hipStream_t stream) {
    const float* x  = (const float*)d_in[0];
    const int*   ei = (const int*)d_in[1];
    const float* W1 = (const float*)d_in[2];
    const float* W2 = (const float*)d_in[3];
    const float* W3 = (const float*)d_in[4];
    float* out = (float*)d_out;

    int N = in_sizes[0] / DIN;
    int E = in_sizes[1] / 2;
    const int* row = ei;         // sources
    const int* col = ei + E;     // targets (aggregation)

    char* ws = (char*)d_ws;
    int*   deg     = (int*)ws;                      // N ints (later: fill cursor)
    float* dinv    = (float*)(ws + 400000);         // N floats
    int*   rowptr  = (int*)(ws + 800000);           // N+1 ints
    int*   csr_src = (int*)(ws + 1200016);          // E ints
    float* csr_w   = (float*)(ws + 7600016);        // E floats
    unsigned short* bufA = (unsigned short*)(ws + 14000128);  // N*256 fp16 agg out (A operand)
    unsigned short* w1h  = (unsigned short*)(ws + 65200128);  // 256*128 fp16
    unsigned short* w2h  = (unsigned short*)(ws + 65265664);  // 256*256 fp16
    unsigned short* w3h  = (unsigned short*)(ws + 65396736);  // 256*256 fp16
    int*   bsum    = (int*)(ws + 65527808);         // ~(N/1024)+1 ints, scan block sums

    // fp16 staging for gather inputs lives inside d_out (dead/overwritten):
    // x_f16 (N*128, 25.6MB) is dead before GEMM1 writes h (N*256 fp16, 51.2MB)
    // over it; GEMM3 fully overwrites d_out with the fp32 result.
    unsigned short* hb = (unsigned short*)d_out;

    dim3 b256(256);
    int nb = (N + 1023) / 1024;                     // scan blocks (98 @ N=100K)

    // CSR build: deg -> rowptr (3-phase scan, dinv+cursor fused) -> fill
    zero_int_kernel<<<dim3((N + 255) / 256), b256, 0, stream>>>(deg, N);
    count_deg_kernel<<<dim3((E + 255) / 256), b256, 0, stream>>>(col, E, deg);
    scan_p1_kernel<<<dim3(nb), b256, 0, stream>>>(deg, bsum, N);
    scan_p2_kernel<<<dim3(1), dim3(1024), 0, stream>>>(bsum, nb);
    scan_p3_kernel<<<dim3(nb), b256, 0, stream>>>(deg, bsum, rowptr, dinv, N, E);
    fill_csr_kernel<<<dim3((E + 255) / 256), b256, 0, stream>>>(
        row, col, rowptr, deg, dinv, csr_src, csr_w, E);

    // Pre-cast weights + x to fp16
    cast_f16_kernel<<<dim3((N * (DIN / 4) + 255) / 256), b256, 0, stream>>>(
        (const float4*)x, (ushort4*)hb, N * (DIN / 4));
    cast_f16_kernel<<<dim3((DH * DIN / 4 + 255) / 256), b256, 0, stream>>>(
        (const float4*)W1, (ushort4*)w1h, DH * DIN / 4);
    cast_f16_kernel<<<dim3((DH * DH / 4 + 255) / 256), b256, 0, stream>>>(
        (const float4*)W2, (ushort4*)w2h, DH * DH / 4);
    cast_f16_kernel<<<dim3((DH * DH / 4 + 255) / 256), b256, 0, stream>>>(
        (const float4*)W3, (ushort4*)w3h, DH * DH / 4);

    dim3 ggrid((N + 127) / 128, 2);

    // ---- Layer 1: s = A_n x16; h1 = f16(relu(s @ W1^T))
    agg_gather_f16_kernel<DIN><<<dim3((N + 7) / 8), b256, 0, stream>>>(
        rowptr, csr_src, csr_w, dinv, (const ushort4*)hb, (ushort4*)bufA, N);
    gemm_nt_mfma_kernel<DIN, true, unsigned short><<<ggrid, b256, 0, stream>>>(
        bufA, w1h, hb, N);

    // ---- Layer 2: s = A_n h1; h2 = f16(relu(s @ W2^T))
    agg_gather_f16_kernel<DH><<<dim3((N + 3) / 4), b256, 0, stream>>>(
        rowptr, csr_src, csr_w, dinv, (const ushort4*)hb, (ushort4*)bufA, N);
    gemm_nt_mfma_kernel<DH, true, unsigned short><<<ggrid, b256, 0, stream>>>(
        bufA, w2h, hb, N);

    // ---- Layer 3: s = A_n h2; out = s @ W3^T (fp32, full overwrite of d_out)
    agg_gather_f16_kernel<DH><<<dim3((N + 3) / 4), b256, 0, stream>>>(
        rowptr, csr_src, csr_w, dinv, (const ushort4*)hb, (ushort4*)bufA, N);
    gemm_nt_mfma_kernel<DH, false, float><<<ggrid, b256, 0, stream>>>(
        bufA, w3h, out, N);
}

// Round 3
// 708.909 us; speedup vs baseline: 1.7932x; 1.0494x over previous
//
#include <hip/hip_runtime.h>

// ---------------------------------------------------------------------------
// GCN 3-layer forward on MI355X — Round 7: MLP-unrolled gather.
// R6 counters: agg_gather<256> = 127.7us, FETCH 406MB, hbm 3.66TB/s (46%),
// VALUBusy 29%, VGPR=12 -> compiler kept the edge loop serial: ~1 gather in
// flight per wave, 49 CU-cycles/edge = pure latency x MLP bound, NOT bytes.
// Fix: unroll the broadcast-gather loop x8 (8 readlane/shfl broadcasts, 8
// independent 8B loads issued back-to-back, then FMA consume). MLP 1 -> 8.
// Scan (R6), fp16 MFMA GEMM (R5), CSR build unchanged.
// ---------------------------------------------------------------------------

constexpr int DIN = 128;
constexpr int DH  = 256;

typedef _Float16 f16x8 __attribute__((ext_vector_type(8)));
typedef float    f32x4 __attribute__((ext_vector_type(4)));

__device__ __forceinline__ float h2f(unsigned short u) {
    _Float16 h;
    __builtin_memcpy(&h, &u, 2);
    return (float)h;
}
__device__ __forceinline__ unsigned short f2h(float f) {
    _Float16 h = (_Float16)f;
    unsigned short u;
    __builtin_memcpy(&u, &h, 2);
    return u;
}

__global__ void zero_int_kernel(int* __restrict__ p, int n) {
    int i = blockIdx.x * blockDim.x + threadIdx.x;
    if (i < n) p[i] = 0;
}

__global__ void count_deg_kernel(const int* __restrict__ col, int E, int* __restrict__ deg) {
    int e = blockIdx.x * blockDim.x + threadIdx.x;
    if (e < E) atomicAdd(&deg[col[e]], 1);
}

// ---- 3-phase multi-block exclusive scan over deg[0..N) -> rowptr[0..N] ----
__global__ __launch_bounds__(256) void scan_p1_kernel(const int* __restrict__ deg,
                                                      int* __restrict__ bsum, int N) {
    int t = threadIdx.x;
    int base = blockIdx.x * 1024 + t * 4;
    int s = 0;
    #pragma unroll
    for (int k = 0; k < 4; k++) { int i = base + k; if (i < N) s += deg[i]; }
    __shared__ int red[256];
    red[t] = s;
    __syncthreads();
    for (int off = 128; off > 0; off >>= 1) {
        if (t < off) red[t] += red[t + off];
        __syncthreads();
    }
    if (t == 0) bsum[blockIdx.x] = red[0];
}

__global__ __launch_bounds__(1024) void scan_p2_kernel(int* __restrict__ bsum, int nb) {
    __shared__ int sums[1024];
    int t = threadIdx.x;
    int chunk = (nb + 1023) / 1024;
    int s0 = t * chunk, s1 = min(nb, s0 + chunk);
    int local = 0;
    for (int i = s0; i < s1; i++) local += bsum[i];
    sums[t] = local;
    __syncthreads();
    for (int off = 1; off < 1024; off <<= 1) {
        int v = (t >= off) ? sums[t - off] : 0;
        __syncthreads();
        sums[t] += v;
        __syncthreads();
    }
    int prefix = (t == 0) ? 0 : sums[t - 1];
    for (int i = s0; i < s1; i++) { int v = bsum[i]; bsum[i] = prefix; prefix += v; }
}

// Phase 3: block-local exclusive scan + bsum[b] offset -> rowptr.
// Fused: dinv[i] = 1/sqrt(deg[i]+1), deg[i] = 0 (CSR fill cursor reset).
__global__ __launch_bounds__(256) void scan_p3_kernel(int* __restrict__ deg,
                                                      const int* __restrict__ bsum,
                                                      int* __restrict__ rowptr,
                                                      float* __restrict__ dinv,
                                                      int N, int E) {
    int t = threadIdx.x;
    int base = blockIdx.x * 1024 + t * 4;
    int v[4];
    int s = 0;
    #pragma unroll
    for (int k = 0; k < 4; k++) {
        int i = base + k;
        v[k] = (i < N) ? deg[i] : 0;
        s += v[k];
    }
    __shared__ int sums[256];
    sums[t] = s;
    __syncthreads();
    for (int off = 1; off < 256; off <<= 1) {
        int u = (t >= off) ? sums[t - off] : 0;
        __syncthreads();
        sums[t] += u;
        __syncthreads();
    }
    int prefix = bsum[blockIdx.x] + ((t == 0) ? 0 : sums[t - 1]);
    #pragma unroll
    for (int k = 0; k < 4; k++) {
        int i = base + k;
        if (i < N) {
            rowptr[i] = prefix;
            dinv[i] = 1.0f / sqrtf((float)(v[k] + 1));
            deg[i] = 0;
        }
        prefix += v[k];
    }
    if (blockIdx.x == 0 && t == 0) rowptr[N] = E;
}

__global__ void fill_csr_kernel(const int* __restrict__ row, const int* __restrict__ col,
                                const int* __restrict__ rowptr, int* __restrict__ cnt,
                                const float* __restrict__ dinv,
                                int* __restrict__ csr_src, float* __restrict__ csr_w, int E) {
    int e = blockIdx.x * blockDim.x + threadIdx.x;
    if (e >= E) return;
    int r = row[e], c = col[e];
    int pos = rowptr[c] + atomicAdd(&cnt[c], 1);
    csr_src[pos] = r;
    csr_w[pos]   = dinv[r] * dinv[c];
}

// fp32 -> fp16 cast (RNE), 4 elems/thread.
__global__ void cast_f16_kernel(const float4* __restrict__ in, ushort4* __restrict__ out, int n4) {
    int i = blockIdx.x * blockDim.x + threadIdx.x;
    if (i >= n4) return;
    float4 v = in[i];
    ushort4 o;
    o.x = f2h(v.x); o.y = f2h(v.y); o.z = f2h(v.z); o.w = f2h(v.w);
    out[i] = o;
}

// One L-lane group per node; lane handles 4 fp16 elems (8B load). L = D/4.
// in: fp16 rows [N][D]; out: fp16 rows [N][D]. Self-loop fused into init.
// Inner edge loop unrolled x8: 8 broadcasts -> 8 independent loads in flight
// -> FMA consume. (R6 was MLP=1, latency-bound at 49 CU-cyc/edge.)
template<int D>
__global__ __launch_bounds__(256) void agg_gather_f16_kernel(const int* __restrict__ rowptr,
                                                             const int* __restrict__ csr_src,
                                                             const float* __restrict__ csr_w,
                                                             const float* __restrict__ dinv,
                                                             const ushort4* __restrict__ in,
                                                             ushort4* __restrict__ out, int N) {
    constexpr int L = D / 4;                 // 64 (D=256) or 32 (D=128)
    constexpr int GPB = 256 / L;
    int n = blockIdx.x * GPB + threadIdx.x / L;
    if (n >= N) return;
    int lane = threadIdx.x % L;

    float di = dinv[n];
    float s = di * di;
    ushort4 sv = in[(size_t)n * L + lane];
    float4 acc = make_float4(h2f(sv.x) * s, h2f(sv.y) * s, h2f(sv.z) * s, h2f(sv.w) * s);

    int start = rowptr[n], end = rowptr[n + 1];
    for (int j0 = start; j0 < end; j0 += L) {
        int nb = end - j0; if (nb > L) nb = L;
        int   src = 0;
        float w   = 0.0f;
        if (lane < nb) { src = csr_src[j0 + lane]; w = csr_w[j0 + lane]; }

        int t = 0;
        for (; t + 8 <= nb; t += 8) {
            int   rr[8];
            float wv[8];
            #pragma unroll
            for (int u = 0; u < 8; ++u) {
                if constexpr (L == 64) {
                    rr[u] = __builtin_amdgcn_readlane(src, t + u);
                    wv[u] = __int_as_float(__builtin_amdgcn_readlane(__float_as_int(w), t + u));
                } else {
                    rr[u] = __shfl(src, t + u, L);
                    wv[u] = __shfl(w,   t + u, L);
                }
            }
            ushort4 vv[8];
            #pragma unroll
            for (int u = 0; u < 8; ++u) vv[u] = in[(size_t)rr[u] * L + lane];
            #pragma unroll
            for (int u = 0; u < 8; ++u) {
                acc.x += wv[u] * h2f(vv[u].x);
                acc.y += wv[u] * h2f(vv[u].y);
                acc.z += wv[u] * h2f(vv[u].z);
                acc.w += wv[u] * h2f(vv[u].w);
            }
        }
        for (; t < nb; ++t) {
            int   r;
            float ww;
            if constexpr (L == 64) {
                r  = __builtin_amdgcn_readlane(src, t);
                ww = __int_as_float(__builtin_amdgcn_readlane(__float_as_int(w), t));
            } else {
                r  = __shfl(src, t, L);
                ww = __shfl(w,   t, L);
            }
            ushort4 v = in[(size_t)r * L + lane];
            acc.x += ww * h2f(v.x); acc.y += ww * h2f(v.y);
            acc.z += ww * h2f(v.z); acc.w += ww * h2f(v.w);
        }
    }
    ushort4 o;
    o.x = f2h(acc.x); o.y = f2h(acc.y); o.z = f2h(acc.z); o.w = f2h(acc.w);
    out[(size_t)n * L + lane] = o;
}

// C[n][m] = sum_k A[n][k]*W[m][k]; A:[N,K] fp16, W:[256,K] fp16 (pre-cast).
// MFMA f16, fp32 accum. 128x128 tile, BK=64, 4 waves (2x2), 64x64 per wave.
// LDS: A-tile + W-tile, [128][64] fp16, XOR-swizzled 16B slots
// (slot ^= row&7) -> 2-way max bank aliasing on ds_read_b128 (free, m136).
template<int K, bool RELU, typename OT>
__global__ __launch_bounds__(256) void gemm_nt_mfma_kernel(const unsigned short* __restrict__ A,
                                                           const unsigned short* __restrict__ Wh,
                                                           OT* __restrict__ C, int N) {
    __shared__ __align__(16) unsigned short As[128 * 64];
    __shared__ __align__(16) unsigned short Ws[128 * 64];
    int tid  = threadIdx.x;
    int lane = tid & 63;
    int wave = tid >> 6;
    int wr = wave >> 1, wc = wave & 1;       // wave grid 2x2
    int m0 = blockIdx.x * 128;               // output rows (nodes)
    int c0 = blockIdx.y * 128;               // output cols (0 or 128)

    f32x4 acc[4][4];
    #pragma unroll
    for (int i = 0; i < 4; i++)
        #pragma unroll
        for (int j = 0; j < 4; j++)
            #pragma unroll
            for (int r = 0; r < 4; r++) acc[i][j][r] = 0.0f;

    int srow  = tid >> 3;                    // 0..31: staging row within pass
    int sslot = tid & 7;                     // 16B slot within row (8 slots = 64 fp16)

    for (int k0 = 0; k0 < K; k0 += 64) {
        // ---- stage A[m0..m0+127][k0..k0+63] and W[c0..c0+127][k0..k0+63]
        #pragma unroll
        for (int q = 0; q < 4; ++q) {
            int row = q * 32 + srow;
            int byteoff = row * 128 + ((sslot ^ (row & 7)) << 4);
            int gr = m0 + row;
            if (gr >= N) gr = N - 1;         // clamp: tail rows computed, never stored
            f16x8 va = *(const f16x8*)(A + (size_t)gr * K + k0 + sslot * 8);
            *(f16x8*)((char*)As + byteoff) = va;
            int gw = c0 + row;               // always < 256
            f16x8 vw = *(const f16x8*)(Wh + (size_t)gw * K + k0 + sslot * 8);
            *(f16x8*)((char*)Ws + byteoff) = vw;
        }
        __syncthreads();

        // ---- 2 x K=32 MFMA steps over this BK=64 tile
        #pragma unroll
        for (int kk = 0; kk < 2; ++kk) {
            int slot = kk * 4 + (lane >> 4);
            f16x8 a[4], b[4];
            #pragma unroll
            for (int i = 0; i < 4; i++) {
                int row = wr * 64 + i * 16 + (lane & 15);
                a[i] = *(const f16x8*)((const char*)As + row * 128 + ((slot ^ (row & 7)) << 4));
            }
            #pragma unroll
            for (int j = 0; j < 4; j++) {
                int row = wc * 64 + j * 16 + (lane & 15);
                b[j] = *(const f16x8*)((const char*)Ws + row * 128 + ((slot ^ (row & 7)) << 4));
            }
            #pragma unroll
            for (int i = 0; i < 4; i++)
                #pragma unroll
                for (int j = 0; j < 4; j++)
                    acc[i][j] = __builtin_amdgcn_mfma_f32_16x16x32_f16(a[i], b[j], acc[i][j], 0, 0, 0);
        }
        __syncthreads();
    }

    // ---- epilogue: D lane map (verified m89): col = lane&15, row = (lane>>4)*4 + r
    int r4 = (lane >> 4) * 4;
    int cn = lane & 15;
    #pragma unroll
    for (int i = 0; i < 4; i++) {
        #pragma unroll
        for (int r = 0; r < 4; r++) {
            int g_r = m0 + wr * 64 + i * 16 + r4 + r;
            if (g_r >= N) continue;
            #pragma unroll
            for (int j = 0; j < 4; j++) {
                float v = acc[i][j][r];
                if (RELU) v = fmaxf(v, 0.f);
                int col = c0 + wc * 64 + j * 16 + cn;
                if constexpr (sizeof(OT) == 4) {
                    ((float*)C)[(size_t)g_r * DH + col] = v;
                } else {
                    ((unsigned short*)C)[(size_t)g_r * DH + col] = f2h(v);
                }
            }
        }
    }
}

extern "C" void kernel_launch(void* const* d_in, const int* in_sizes, int n_in,
                              void* d_out, int out_size, void* d_ws, size_t ws_size,
                              hipStream_t stream) {
    const float* x  = (const float*)d_in[0];
    const int*   ei = (const int*)d_in[1];
    const float* W1 = (const float*)d_in[2];
    const float* W2 = (const float*)d_in[3];
    const float* W3 = (const float*)d_in[4];
    float* out = (float*)d_out;

    int N = in_sizes[0] / DIN;
    int E = in_sizes[1] / 2;
    const int* row = ei;         // sources
    const int* col = ei + E;     // targets (aggregation)

    char* ws = (char*)d_ws;
    int*   deg     = (int*)ws;                      // N ints (later: fill cursor)
    float* dinv    = (float*)(ws + 400000);         // N floats
    int*   rowptr  = (int*)(ws + 800000);           // N+1 ints
    int*   csr_src = (int*)(ws + 1200016);          // E ints
    float* csr_w   = (float*)(ws + 7600016);        // E floats
    unsigned short* bufA = (unsigned short*)(ws + 14000128);  // N*256 fp16 agg out (A operand)
    unsigned short* w1h  = (unsigned short*)(ws + 65200128);  // 256*128 fp16
    unsigned short* w2h  = (unsigned short*)(ws + 65265664);  // 256*256 fp16
    unsigned short* w3h  = (unsigned short*)(ws + 65396736);  // 256*256 fp16
    int*   bsum    = (int*)(ws + 65527808);         // ~(N/1024)+1 ints, scan block sums

    // fp16 staging for gather inputs lives inside d_out (dead/overwritten):
    // x_f16 (N*128, 25.6MB) is dead before GEMM1 writes h (N*256 fp16, 51.2MB)
    // over it; GEMM3 fully overwrites d_out with the fp32 result.
    unsigned short* hb = (unsigned short*)d_out;

    dim3 b256(256);
    int nb = (N + 1023) / 1024;                     // scan blocks (98 @ N=100K)

    // CSR build: deg -> rowptr (3-phase scan, dinv+cursor fused) -> fill
    zero_int_kernel<<<dim3((N + 255) / 256), b256, 0, stream>>>(deg, N);
    count_deg_kernel<<<dim3((E + 255) / 256), b256, 0, stream>>>(col, E, deg);
    scan_p1_kernel<<<dim3(nb), b256, 0, stream>>>(deg, bsum, N);
    scan_p2_kernel<<<dim3(1), dim3(1024), 0, stream>>>(bsum, nb);
    scan_p3_kernel<<<dim3(nb), b256, 0, stream>>>(deg, bsum, rowptr, dinv, N, E);
    fill_csr_kernel<<<dim3((E + 255) / 256), b256, 0, stream>>>(
        row, col, rowptr, deg, dinv, csr_src, csr_w, E);

    // Pre-cast weights + x to fp16
    cast_f16_kernel<<<dim3((N * (DIN / 4) + 255) / 256), b256, 0, stream>>>(
        (const float4*)x, (ushort4*)hb, N * (DIN / 4));
    cast_f16_kernel<<<dim3((DH * DIN / 4 + 255) / 256), b256, 0, stream>>>(
        (const float4*)W1, (ushort4*)w1h, DH * DIN / 4);
    cast_f16_kernel<<<dim3((DH * DH / 4 + 255) / 256), b256, 0, stream>>>(
        (const float4*)W2, (ushort4*)w2h, DH * DH / 4);
    cast_f16_kernel<<<dim3((DH * DH / 4 + 255) / 256), b256, 0, stream>>>(
        (const float4*)W3, (ushort4*)w3h, DH * DH / 4);

    dim3 ggrid((N + 127) / 128, 2);

    // ---- Layer 1: s = A_n x16; h1 = f16(relu(s @ W1^T))
    agg_gather_f16_kernel<DIN><<<dim3((N + 7) / 8), b256, 0, stream>>>(
        rowptr, csr_src, csr_w, dinv, (const ushort4*)hb, (ushort4*)bufA, N);
    gemm_nt_mfma_kernel<DIN, true, unsigned short><<<ggrid, b256, 0, stream>>>(
        bufA, w1h, hb, N);

    // ---- Layer 2: s = A_n h1; h2 = f16(relu(s @ W2^T))
    agg_gather_f16_kernel<DH><<<dim3((N + 3) / 4), b256, 0, stream>>>(
        rowptr, csr_src, csr_w, dinv, (const ushort4*)hb, (ushort4*)bufA, N);
    gemm_nt_mfma_kernel<DH, true, unsigned short><<<ggrid, b256, 0, stream>>>(
        bufA, w2h, hb, N);

    // ---- Layer 3: s = A_n h2; out = s @ W3^T (fp32, full overwrite of d_out)
    agg_gather_f16_kernel<DH><<<dim3((N + 3) / 4), b256, 0, stream>>>(
        rowptr, csr_src, csr_w, dinv, (const ushort4*)hb, (ushort4*)bufA, N);
    gemm_nt_mfma_kernel<DH, false, float><<<ggrid, b256, 0, stream>>>(
        bufA, w3h, out, N);
}

// Round 4
// 644.183 us; speedup vs baseline: 1.9734x; 1.1005x over previous
//
#include <hip/hip_runtime.h>

// ---------------------------------------------------------------------------
// GCN 3-layer forward on MI355X — Round 8: atomic-free CSR fill + folded norm.
// R7 counters: fill_csr = 123.9us (VALUBusy 0.6%, WRITE 155MB) -- dependent
// atomicAdd round-trip + 2 random 4B scatters per edge. Fixes:
//  (1) count_deg stores its atomicAdd RETURN as seq[e] -> fill needs no atomic.
//  (2) csr_w deleted: gather inputs pre-scaled by dinv (x~ = dinv*x at cast,
//      h~ = dinv*relu(gemm) in epilogue); s[n] = dinv[n]*(sum x~[src] + x~[n]).
//      Gather has NO per-edge weight: 1 readlane + 4 cvt-adds per edge.
//  (3) GEMM 1D grid with XCD-pairing decode: (cx,cy=0)/(cx,cy=1) land 8 hw
//      indices apart -> same XCD -> 2nd A-tile read is an L2 hit.
// Gather itself left alone (R7 showed it's on the random LLC-path ceiling).
// ---------------------------------------------------------------------------

constexpr int DIN = 128;
constexpr int DH  = 256;

typedef _Float16 f16x8 __attribute__((ext_vector_type(8)));
typedef float    f32x4 __attribute__((ext_vector_type(4)));

__device__ __forceinline__ float h2f(unsigned short u) {
    _Float16 h;
    __builtin_memcpy(&h, &u, 2);
    return (float)h;
}
__device__ __forceinline__ unsigned short f2h(float f) {
    _Float16 h = (_Float16)f;
    unsigned short u;
    __builtin_memcpy(&u, &h, 2);
    return u;
}

__global__ void zero_int_kernel(int* __restrict__ p, int n) {
    int i = blockIdx.x * blockDim.x + threadIdx.x;
    if (i < n) p[i] = 0;
}

// Degree count; atomic return value = within-node slot -> seq[e].
__global__ void count_deg_kernel(const int* __restrict__ col, int E,
                                 int* __restrict__ deg, int* __restrict__ seq) {
    int e = blockIdx.x * blockDim.x + threadIdx.x;
    if (e < E) seq[e] = atomicAdd(&deg[col[e]], 1);
}

// ---- 3-phase multi-block exclusive scan over deg[0..N) -> rowptr[0..N] ----
__global__ __launch_bounds__(256) void scan_p1_kernel(const int* __restrict__ deg,
                                                      int* __restrict__ bsum, int N) {
    int t = threadIdx.x;
    int base = blockIdx.x * 1024 + t * 4;
    int s = 0;
    #pragma unroll
    for (int k = 0; k < 4; k++) { int i = base + k; if (i < N) s += deg[i]; }
    __shared__ int red[256];
    red[t] = s;
    __syncthreads();
    for (int off = 128; off > 0; off >>= 1) {
        if (t < off) red[t] += red[t + off];
        __syncthreads();
    }
    if (t == 0) bsum[blockIdx.x] = red[0];
}

__global__ __launch_bounds__(1024) void scan_p2_kernel(int* __restrict__ bsum, int nb) {
    __shared__ int sums[1024];
    int t = threadIdx.x;
    int chunk = (nb + 1023) / 1024;
    int s0 = t * chunk, s1 = min(nb, s0 + chunk);
    int local = 0;
    for (int i = s0; i < s1; i++) local += bsum[i];
    sums[t] = local;
    __syncthreads();
    for (int off = 1; off < 1024; off <<= 1) {
        int v = (t >= off) ? sums[t - off] : 0;
        __syncthreads();
        sums[t] += v;
        __syncthreads();
    }
    int prefix = (t == 0) ? 0 : sums[t - 1];
    for (int i = s0; i < s1; i++) { int v = bsum[i]; bsum[i] = prefix; prefix += v; }
}

// Phase 3: block-local exclusive scan + bsum[b] offset -> rowptr.
// Fused: dinv[i] = 1/sqrt(deg[i]+1).
__global__ __launch_bounds__(256) void scan_p3_kernel(const int* __restrict__ deg,
                                                      const int* __restrict__ bsum,
                                                      int* __restrict__ rowptr,
                                                      float* __restrict__ dinv,
                                                      int N, int E) {
    int t = threadIdx.x;
    int base = blockIdx.x * 1024 + t * 4;
    int v[4];
    int s = 0;
    #pragma unroll
    for (int k = 0; k < 4; k++) {
        int i = base + k;
        v[k] = (i < N) ? deg[i] : 0;
        s += v[k];
    }
    __shared__ int sums[256];
    sums[t] = s;
    __syncthreads();
    for (int off = 1; off < 256; off <<= 1) {
        int u = (t >= off) ? sums[t - off] : 0;
        __syncthreads();
        sums[t] += u;
        __syncthreads();
    }
    int prefix = bsum[blockIdx.x] + ((t == 0) ? 0 : sums[t - 1]);
    #pragma unroll
    for (int k = 0; k < 4; k++) {
        int i = base + k;
        if (i < N) {
            rowptr[i] = prefix;
            dinv[i] = 1.0f / sqrtf((float)(v[k] + 1));
        }
        prefix += v[k];
    }
    if (blockIdx.x == 0 && t == 0) rowptr[N] = E;
}

// Atomic-free: pos = rowptr[col] + seq (seq captured in count_deg).
__global__ void fill_csr_kernel(const int* __restrict__ row, const int* __restrict__ col,
                                const int* __restrict__ seq, const int* __restrict__ rowptr,
                                int* __restrict__ csr_src, int E) {
    int e = blockIdx.x * blockDim.x + threadIdx.x;
    if (e >= E) return;
    int c = col[e];
    csr_src[rowptr[c] + seq[e]] = row[e];
}

// fp32 -> fp16 cast (RNE), 4 elems/thread.
__global__ void cast_f16_kernel(const float4* __restrict__ in, ushort4* __restrict__ out, int n4) {
    int i = blockIdx.x * blockDim.x + threadIdx.x;
    if (i >= n4) return;
    float4 v = in[i];
    ushort4 o;
    o.x = f2h(v.x); o.y = f2h(v.y); o.z = f2h(v.z); o.w = f2h(v.w);
    out[i] = o;
}

// x~ = dinv[row] * x, fp16. Row of elem group i (4 fp32) = i / (DIN/4).
__global__ void cast_f16_scaled_kernel(const float4* __restrict__ in,
                                       const float* __restrict__ dinv,
                                       ushort4* __restrict__ out, int n4) {
    int i = blockIdx.x * blockDim.x + threadIdx.x;
    if (i >= n4) return;
    float s = dinv[i >> 5];                  // DIN/4 = 32 groups per row
    float4 v = in[i];
    ushort4 o;
    o.x = f2h(v.x * s); o.y = f2h(v.y * s); o.z = f2h(v.z * s); o.w = f2h(v.w * s);
    out[i] = o;
}

// One L-lane group per node; lane handles 4 fp16 elems (8B load). L = D/4.
// in: PRE-SCALED fp16 rows (x~ or h~); out[n] = f2h(dinv[n] * (sum + self)).
// No per-edge weight. Unroll x8 for MLP.
template<int D>
__global__ __launch_bounds__(256) void agg_gather_f16_kernel(const int* __restrict__ rowptr,
                                                             const int* __restrict__ csr_src,
                                                             const float* __restrict__ dinv,
                                                             const ushort4* __restrict__ in,
                                                             ushort4* __restrict__ out, int N) {
    constexpr int L = D / 4;                 // 64 (D=256) or 32 (D=128)
    constexpr int GPB = 256 / L;
    int n = blockIdx.x * GPB + threadIdx.x / L;
    if (n >= N) return;
    int lane = threadIdx.x % L;

    ushort4 sv = in[(size_t)n * L + lane];
    float4 acc = make_float4(h2f(sv.x), h2f(sv.y), h2f(sv.z), h2f(sv.w));

    int start = rowptr[n], end = rowptr[n + 1];
    for (int j0 = start; j0 < end; j0 += L) {
        int nb = end - j0; if (nb > L) nb = L;
        int src = (lane < nb) ? csr_src[j0 + lane] : 0;

        int t = 0;
        for (; t + 8 <= nb; t += 8) {
            int rr[8];
            #pragma unroll
            for (int u = 0; u < 8; ++u) {
                if constexpr (L == 64) rr[u] = __builtin_amdgcn_readlane(src, t + u);
                else                   rr[u] = __shfl(src, t + u, L);
            }
            ushort4 vv[8];
            #pragma unroll
            for (int u = 0; u < 8; ++u) vv[u] = in[(size_t)rr[u] * L + lane];
            #pragma unroll
            for (int u = 0; u < 8; ++u) {
                acc.x += h2f(vv[u].x);
                acc.y += h2f(vv[u].y);
                acc.z += h2f(vv[u].z);
                acc.w += h2f(vv[u].w);
            }
        }
        for (; t < nb; ++t) {
            int r;
            if constexpr (L == 64) r = __builtin_amdgcn_readlane(src, t);
            else                   r = __shfl(src, t, L);
            ushort4 v = in[(size_t)r * L + lane];
            acc.x += h2f(v.x); acc.y += h2f(v.y);
            acc.z += h2f(v.z); acc.w += h2f(v.w);
        }
    }
    float s = dinv[n];
    ushort4 o;
    o.x = f2h(acc.x * s); o.y = f2h(acc.y * s); o.z = f2h(acc.z * s); o.w = f2h(acc.w * s);
    out[(size_t)n * L + lane] = o;
}

// C[n][m] = sum_k A[n][k]*W[m][k]; A:[N,K] fp16, W:[256,K] fp16 (pre-cast).
// MFMA f16, fp32 accum. 128x128 tile, BK=64, 4 waves (2x2), 64x64 per wave.
// 1D grid, XCD-pairing decode: hw blocks 16g+r and 16g+r+8 (same XCD under
// round-robin) share cx -> second A-tile read hits that XCD's L2.
// SCALE: multiply output row by dinv[row] before fp16 store (h~ = dinv*relu).
template<int K, bool RELU, bool SCALE, typename OT>
__global__ __launch_bounds__(256) void gemm_nt_mfma_kernel(const unsigned short* __restrict__ A,
                                                           const unsigned short* __restrict__ Wh,
                                                           OT* __restrict__ C,
                                                           const float* __restrict__ dinv, int N) {
    __shared__ __align__(16) unsigned short As[128 * 64];
    __shared__ __align__(16) unsigned short Ws[128 * 64];
    int tid  = threadIdx.x;
    int lane = tid & 63;
    int wave = tid >> 6;
    int wr = wave >> 1, wc = wave & 1;       // wave grid 2x2

    // ---- XCD-pairing block decode
    int nwgx = (N + 127) / 128;
    int T = (2 * nwgx) & ~15;
    int b = blockIdx.x;
    int cx, cy;
    if (b < T) { cx = (b >> 4) * 8 + (b & 7); cy = (b >> 3) & 1; }
    else       { int rem = b - T; cx = (T >> 1) + (rem >> 1); cy = rem & 1; }
    int m0 = cx * 128;                       // output rows (nodes)
    int c0 = cy * 128;                       // output cols (0 or 128)

    f32x4 acc[4][4];
    #pragma unroll
    for (int i = 0; i < 4; i++)
        #pragma unroll
        for (int j = 0; j < 4; j++)
            #pragma unroll
            for (int r = 0; r < 4; r++) acc[i][j][r] = 0.0f;

    int srow  = tid >> 3;                    // 0..31: staging row within pass
    int sslot = tid & 7;                     // 16B slot within row (8 slots = 64 fp16)

    for (int k0 = 0; k0 < K; k0 += 64) {
        // ---- stage A[m0..m0+127][k0..k0+63] and W[c0..c0+127][k0..k0+63]
        #pragma unroll
        for (int q = 0; q < 4; ++q) {
            int row = q * 32 + srow;
            int byteoff = row * 128 + ((sslot ^ (row & 7)) << 4);
            int gr = m0 + row;
            if (gr >= N) gr = N - 1;         // clamp: tail rows computed, never stored
            f16x8 va = *(const f16x8*)(A + (size_t)gr * K + k0 + sslot * 8);
            *(f16x8*)((char*)As + byteoff) = va;
            int gw = c0 + row;               // always < 256
            f16x8 vw = *(const f16x8*)(Wh + (size_t)gw * K + k0 + sslot * 8);
            *(f16x8*)((char*)Ws + byteoff) = vw;
        }
        __syncthreads();

        // ---- 2 x K=32 MFMA steps over this BK=64 tile
        #pragma unroll
        for (int kk = 0; kk < 2; ++kk) {
            int slot = kk * 4 + (lane >> 4);
            f16x8 a[4], bfr[4];
            #pragma unroll
            for (int i = 0; i < 4; i++) {
                int row = wr * 64 + i * 16 + (lane & 15);
                a[i] = *(const f16x8*)((const char*)As + row * 128 + ((slot ^ (row & 7)) << 4));
            }
            #pragma unroll
            for (int j = 0; j < 4; j++) {
                int row = wc * 64 + j * 16 + (lane & 15);
                bfr[j] = *(const f16x8*)((const char*)Ws + row * 128 + ((slot ^ (row & 7)) << 4));
            }
            #pragma unroll
            for (int i = 0; i < 4; i++)
                #pragma unroll
                for (int j = 0; j < 4; j++)
                    acc[i][j] = __builtin_amdgcn_mfma_f32_16x16x32_f16(a[i], bfr[j], acc[i][j], 0, 0, 0);
        }
        __syncthreads();
    }

    // ---- epilogue: D lane map (verified m89): col = lane&15, row = (lane>>4)*4 + r
    int r4 = (lane >> 4) * 4;
    int cn = lane & 15;
    #pragma unroll
    for (int i = 0; i < 4; i++) {
        #pragma unroll
        for (int r = 0; r < 4; r++) {
            int g_r = m0 + wr * 64 + i * 16 + r4 + r;
            if (g_r >= N) continue;
            float dv = SCALE ? dinv[g_r] : 1.0f;
            #pragma unroll
            for (int j = 0; j < 4; j++) {
                float v = acc[i][j][r];
                if (RELU) v = fmaxf(v, 0.f);
                if (SCALE) v *= dv;
                int col = c0 + wc * 64 + j * 16 + cn;
                if constexpr (sizeof(OT) == 4) {
                    ((float*)C)[(size_t)g_r * DH + col] = v;
                } else {
                    ((unsigned short*)C)[(size_t)g_r * DH + col] = f2h(v);
                }
            }
        }
    }
}

extern "C" void kernel_launch(void* const* d_in, const int* in_sizes, int n_in,
                              void* d_out, int out_size, void* d_ws, size_t ws_size,
                              hipStream_t stream) {
    const float* x  = (const float*)d_in[0];
    const int*   ei = (const int*)d_in[1];
    const float* W1 = (const float*)d_in[2];
    const float* W2 = (const float*)d_in[3];
    const float* W3 = (const float*)d_in[4];
    float* out = (float*)d_out;

    int N = in_sizes[0] / DIN;
    int E = in_sizes[1] / 2;
    const int* row = ei;         // sources
    const int* col = ei + E;     // targets (aggregation)

    char* ws = (char*)d_ws;
    int*   deg     = (int*)ws;                      // N ints
    float* dinv    = (float*)(ws + 400000);         // N floats
    int*   rowptr  = (int*)(ws + 800000);           // N+1 ints
    int*   csr_src = (int*)(ws + 1200016);          // E ints
    int*   seq     = (int*)(ws + 7600016);          // E ints (old csr_w slot)
    unsigned short* bufA = (unsigned short*)(ws + 14000128);  // N*256 fp16 agg out (A operand)
    unsigned short* w1h  = (unsigned short*)(ws + 65200128);  // 256*128 fp16
    unsigned short* w2h  = (unsigned short*)(ws + 65265664);  // 256*256 fp16
    unsigned short* w3h  = (unsigned short*)(ws + 65396736);  // 256*256 fp16
    int*   bsum    = (int*)(ws + 65527808);         // ~(N/1024)+1 ints, scan block sums

    // fp16 staging for gather inputs lives inside d_out (dead/overwritten):
    // x~ (N*128, 25.6MB) is dead before GEMM1 writes h~ (N*256 fp16, 51.2MB)
    // over it; GEMM3 fully overwrites d_out with the fp32 result.
    unsigned short* hb = (unsigned short*)d_out;

    dim3 b256(256);
    int nb = (N + 1023) / 1024;                     // scan blocks (98 @ N=100K)

    // CSR build: deg+seq -> rowptr (3-phase scan, dinv fused) -> atomic-free fill
    zero_int_kernel<<<dim3((N + 255) / 256), b256, 0, stream>>>(deg, N);
    count_deg_kernel<<<dim3((E + 255) / 256), b256, 0, stream>>>(col, E, deg, seq);
    scan_p1_kernel<<<dim3(nb), b256, 0, stream>>>(deg, bsum, N);
    scan_p2_kernel<<<dim3(1), dim3(1024), 0, stream>>>(bsum, nb);
    scan_p3_kernel<<<dim3(nb), b256, 0, stream>>>(deg, bsum, rowptr, dinv, N, E);
    fill_csr_kernel<<<dim3((E + 255) / 256), b256, 0, stream>>>(
        row, col, seq, rowptr, csr_src, E);

    // Pre-cast weights; x~ = dinv*x (scan_p3 produced dinv before this point)
    cast_f16_scaled_kernel<<<dim3((N * (DIN / 4) + 255) / 256), b256, 0, stream>>>(
        (const float4*)x, dinv, (ushort4*)hb, N * (DIN / 4));
    cast_f16_kernel<<<dim3((DH * DIN / 4 + 255) / 256), b256, 0, stream>>>(
        (const float4*)W1, (ushort4*)w1h, DH * DIN / 4);
    cast_f16_kernel<<<dim3((DH * DH / 4 + 255) / 256), b256, 0, stream>>>(
        (const float4*)W2, (ushort4*)w2h, DH * DH / 4);
    cast_f16_kernel<<<dim3((DH * DH / 4 + 255) / 256), b256, 0, stream>>>(
        (const float4*)W3, (ushort4*)w3h, DH * DH / 4);

    int nwg = 2 * ((N + 127) / 128);

    // ---- Layer 1: s = dinv*(sum x~); h1~ = dinv*f16(relu(s @ W1^T))
    agg_gather_f16_kernel<DIN><<<dim3((N + 7) / 8), b256, 0, stream>>>(
        rowptr, csr_src, dinv, (const ushort4*)hb, (ushort4*)bufA, N);
    gemm_nt_mfma_kernel<DIN, true, true, unsigned short><<<dim3(nwg), b256, 0, stream>>>(
        bufA, w1h, hb, dinv, N);

    // ---- Layer 2: s = dinv*(sum h1~); h2~ = dinv*f16(relu(s @ W2^T))
    agg_gather_f16_kernel<DH><<<dim3((N + 3) / 4), b256, 0, stream>>>(
        rowptr, csr_src, dinv, (const ushort4*)hb, (ushort4*)bufA, N);
    gemm_nt_mfma_kernel<DH, true, true, unsigned short><<<dim3(nwg), b256, 0, stream>>>(
        bufA, w2h, hb, dinv, N);

    // ---- Layer 3: s = dinv*(sum h2~); out = s @ W3^T (fp32, full overwrite)
    agg_gather_f16_kernel<DH><<<dim3((N + 3) / 4), b256, 0, stream>>>(
        rowptr, csr_src, dinv, (const ushort4*)hb, (ushort4*)bufA, N);
    gemm_nt_mfma_kernel<DH, false, false, float><<<dim3(nwg), b256, 0, stream>>>(
        bufA, w3h, out, dinv, N);
}